// Round 1
// 112.946 us; speedup vs baseline: 1.0134x; 1.0134x over previous
//
#include <hip/hip_runtime.h>

// SplineActivation: out[b,d] = sum_k basis_k(x[b,d]) * coeffs[d,k]
// Uniform cubic B-spline, evaluated as a per-cell Horner cubic:
//   out = p0 + s*(p1 + s*(p2 + s*p3)), cell c = clamp(floor(u),0,3), s = u-c.
// LDS holds, per d, the 4 cells' (p0,p1,p2,p3) as float4 (stride 80 B).
// Slot mapping is TRANSPOSED: d-local dl = 4*l + j lives at slot l + 64*j,
// so a wave's ds_read_b128 addresses step 20 words/lane -> bank-quad step 5
// (gcd(5,8)=1) -> all 8 quads covered uniformly, conflict-free gather.
// Staging thread t writes slot t (same quad-step-5 property on writes).

#define D     4096
#define B     4096
#define NB    7
#define DTILE 256
#define ROWS  16

constexpr int NDT    = D / DTILE;   // 16 d-tiles
constexpr int NRT    = B / ROWS;    // 256 row-tiles
constexpr int STRIDE = 20;          // words per slot: 4 cells * 4 words + 4 pad

__global__ __launch_bounds__(256, 8) void
spline_act_kernel(const float* __restrict__ x,
                  const float* __restrict__ coeffs,
                  float* __restrict__ out) {
    __shared__ float sc[DTILE * STRIDE];   // 20 KB -> 8 blocks/CU

    const int bid   = blockIdx.x;
    const int dt    = bid & (NDT - 1);
    const int rowt  = bid >> 4;
    const int dbase = dt * DTILE;

    // Stage: thread t owns LDS slot t. Slot l + 64*j holds the Horner
    // coefficients for d-local dl = 4*l + j, i.e. thread t stages
    // dl = 4*(t&63) + (t>>6).
    {
        const int t  = threadIdx.x;
        const int dl = 4 * (t & 63) + (t >> 6);
        const float* crow = coeffs + (size_t)(dbase + dl) * NB;
        float cr[7];
#pragma unroll
        for (int k = 0; k < 7; ++k) cr[k] = crow[k];
        float* bp = &sc[t * STRIDE];
        const float k6 = 1.0f / 6.0f;
#pragma unroll
        for (int c = 0; c < 4; ++c) {
            float A  = cr[c];
            float Bv = cr[c + 1];
            float C  = cr[c + 2];
            float Dv = cr[c + 3];
            float p0 = (A + 4.0f * Bv + C) * k6;
            float p1 = (C - A) * 0.5f;
            float p2 = (A + C) * 0.5f - Bv;
            float p3 = (Dv - A + 3.0f * (Bv - C)) * k6;
            *reinterpret_cast<float4*>(bp + 4 * c) = make_float4(p0, p1, p2, p3);
        }
    }
    __syncthreads();

    const int tid  = threadIdx.x;
    const int pos  = tid & 63;     // float4 position within 256-d segment (= lane)
    const int rsub = tid >> 6;     // which of 4 concurrent rows

    const float4* x4 = reinterpret_cast<const float4*>(x);
    float4*       o4 = reinterpret_cast<float4*>(out);

    const int rowbase = rowt * ROWS;

#pragma unroll
    for (int it = 0; it < ROWS / 4; ++it) {
        int row = rowbase + it * 4 + rsub;
        int idx = row * (D / 4) + (dbase >> 2) + pos;

        float4 xv = x4[idx];
        float xs[4] = {xv.x, xv.y, xv.z, xv.w};
        float r[4];

#pragma unroll
        for (int j = 0; j < 4; ++j) {
            float u = (xs[j] + 1.0f) * 2.0f;     // cell coord in [0,4)
            int c = (int)floorf(u);
            c = c < 0 ? 0 : (c > 3 ? 3 : c);
            float s = u - (float)c;

            // transposed slot: lane-major, tap j in the high bits
            const float4 cv = *reinterpret_cast<const float4*>(
                &sc[(pos + (j << 6)) * STRIDE + 4 * c]);
            r[j] = fmaf(fmaf(fmaf(cv.w, s, cv.z), s, cv.y), s, cv.x);
        }

        o4[idx] = make_float4(r[0], r[1], r[2], r[3]);
    }
}

extern "C" void kernel_launch(void* const* d_in, const int* in_sizes, int n_in,
                              void* d_out, int out_size, void* d_ws, size_t ws_size,
                              hipStream_t stream) {
    const float* x      = (const float*)d_in[0];   // (4096, 4096) fp32
    const float* coeffs = (const float*)d_in[1];   // (4096, 7) fp32
    float* out          = (float*)d_out;           // (4096, 4096) fp32

    const int grid = NDT * NRT;   // 4096 blocks x 256 threads
    spline_act_kernel<<<grid, 256, 0, stream>>>(x, coeffs, out);
}